// Round 1
// baseline (552.415 us; speedup 1.0000x reference)
//
#include <hip/hip_runtime.h>

#define BB 64
#define NN 512
#define FF 4
#define INC 64
#define HC 128
#define OUTC 16
#define KK 2048
#define NKT 32  // K-tiles of 64

// Ap layout: [b][kt][i(512)][64 k-els]  bf16, 16B granules XOR-swizzled by (i&7)
// Hs layout: [b][kt][c(128)][64 k-els]  bf16, granules XOR-swizzled by (c&7)

typedef short short8 __attribute__((ext_vector_type(8)));
typedef float f32x4 __attribute__((ext_vector_type(4)));
typedef float f32x2 __attribute__((ext_vector_type(2)));

__device__ __forceinline__ unsigned short f2bf(float x) {
  union { float f; unsigned u; } v;
  v.f = x;
  unsigned r = v.u + 0x7fffu + ((v.u >> 16) & 1u);  // RNE
  return (unsigned short)(r >> 16);
}

__device__ __forceinline__ float silu_f(float x) {
  return x * (1.0f / (1.0f + __expf(-x)));
}

// async global->LDS, 16B per lane; lptr must be wave-uniform (HW adds lane*16)
__device__ __forceinline__ void glds16(const void* g, void* l) {
  __builtin_amdgcn_global_load_lds(
      (const __attribute__((address_space(1))) void*)g,
      (__attribute__((address_space(3))) void*)l, 16, 0, 0);
}

// ---------------------------------------------------------------------------
// Kernel 1 (prep): one wave per (b,i) row.
//   deg[b,i,f] = rsqrt(max(rowsum(adjhat),1))   (adjhat: diag->1)
//   Ap[b][kt][i][:] = bf16(deg_i[f] * adjhat), swizzled granules
// ---------------------------------------------------------------------------
__global__ __launch_bounds__(256) void prep_kernel(
    const float* __restrict__ adj, float* __restrict__ deg,
    unsigned short* __restrict__ Ap) {
  int wave = blockIdx.x * 4 + (threadIdx.x >> 6);
  int lane = threadIdx.x & 63;
  int b = wave >> 9;
  int i = wave & (NN - 1);
  const float4* row = (const float4*)(adj) + (size_t)(b * NN + i) * NN;
  float4 rv[8];
  float4 s = make_float4(0.f, 0.f, 0.f, 0.f);
#pragma unroll
  for (int jj = 0; jj < 8; ++jj) {
    float4 v = row[jj * 64 + lane];
    if (jj * 64 + lane == i) v = make_float4(1.f, 1.f, 1.f, 1.f);  // diag->1
    rv[jj] = v;
    s.x += v.x; s.y += v.y; s.z += v.z; s.w += v.w;
  }
#pragma unroll
  for (int off = 32; off >= 1; off >>= 1) {
    s.x += __shfl_xor(s.x, off);
    s.y += __shfl_xor(s.y, off);
    s.z += __shfl_xor(s.z, off);
    s.w += __shfl_xor(s.w, off);
  }
  float4 d;
  d.x = rsqrtf(fmaxf(s.x, 1.0f));
  d.y = rsqrtf(fmaxf(s.y, 1.0f));
  d.z = rsqrtf(fmaxf(s.z, 1.0f));
  d.w = rsqrtf(fmaxf(s.w, 1.0f));
  int sw = i & 7;
  int pos = ((lane >> 1) & 7) ^ sw;        // swizzled 16B-granule within row
  int half = lane & 1;                     // 8B half of the granule
#pragma unroll
  for (int jj = 0; jj < 8; ++jj) {
    int kt = jj * 4 + (lane >> 4);
    size_t base = ((size_t)(b * NKT + kt) * NN + i) * 64;
    ushort4 o;
    o.x = f2bf(rv[jj].x * d.x);
    o.y = f2bf(rv[jj].y * d.y);
    o.z = f2bf(rv[jj].z * d.z);
    o.w = f2bf(rv[jj].w * d.w);
    *(ushort4*)&Ap[base + pos * 8 + half * 4] = o;
  }
  if (lane == 0) ((float4*)deg)[b * NN + i] = d;
}

// ---------------------------------------------------------------------------
// Kernel 2: Hs[b][kt][c][k] = deg[b,j,f] * (xin[b,j,:] @ W[:,c])  (bf16)
// One block per kt (16 j-rows). Re-tiled 4 rows x 2 cols per thread:
// halves ds_read_b128 count vs 8x1 and makes x-row addrs wave-uniform
// (gg = t>>6 -> pure LDS broadcast reads, conflict-free).
// ---------------------------------------------------------------------------
__global__ __launch_bounds__(256) void lin_hs_kernel(
    const float* __restrict__ xin, const float* __restrict__ W,
    const float* __restrict__ deg, unsigned short* __restrict__ Hs, int CIN) {
  __shared__ float xt[16 * HC];
  int b = blockIdx.y;
  int kt = blockIdx.x;
  int j0 = kt * 16;
  int t = threadIdx.x;
  {
    const f32x4* src = (const f32x4*)(xin + (size_t)(b * NN + j0) * CIN);
    f32x4* dst = (f32x4*)xt;
    int n4 = 16 * CIN / 4;
    for (int idx = t; idx < n4; idx += 256) dst[idx] = src[idx];
  }
  __syncthreads();

  int c2 = (t & 63) * 2;  // 2 consecutive output cols
  int gg = t >> 6;        // wave-uniform row-group: rows gg*4 .. gg*4+3
  const float* xr = &xt[gg * 4 * CIN];
  float acc[4][2];
#pragma unroll
  for (int r = 0; r < 4; ++r) { acc[r][0] = 0.f; acc[r][1] = 0.f; }

  for (int k = 0; k < CIN; k += 4) {
    f32x2 wv[4];
#pragma unroll
    for (int kk = 0; kk < 4; ++kk)
      wv[kk] = *(const f32x2*)&W[(size_t)(k + kk) * HC + c2];
#pragma unroll
    for (int r = 0; r < 4; ++r) {
      f32x4 xv = *(const f32x4*)&xr[r * CIN + k];
#pragma unroll
      for (int kk = 0; kk < 4; ++kk) {
        acc[r][0] = fmaf(xv[kk], wv[kk][0], acc[r][0]);
        acc[r][1] = fmaf(xv[kk], wv[kk][1], acc[r][1]);
      }
    }
  }

  // fold deg_j, pack bf16 granules (same k-order as before -> bitwise-same Hs)
#pragma unroll
  for (int pr = 0; pr < 2; ++pr) {
    int ja = j0 + gg * 4 + pr * 2;
    f32x4 da = *(const f32x4*)&deg[(size_t)(b * NN + ja) * 4];
    f32x4 db = *(const f32x4*)&deg[(size_t)(b * NN + ja + 1) * 4];
    int pairIdx = gg * 2 + pr;
#pragma unroll
    for (int cq = 0; cq < 2; ++cq) {
      int cc = c2 + cq;
      float v0 = acc[pr * 2][cq];
      float v1 = acc[pr * 2 + 1][cq];
      short8 o;
      o[0] = (short)f2bf(v0 * da[0]); o[1] = (short)f2bf(v0 * da[1]);
      o[2] = (short)f2bf(v0 * da[2]); o[3] = (short)f2bf(v0 * da[3]);
      o[4] = (short)f2bf(v1 * db[0]); o[5] = (short)f2bf(v1 * db[1]);
      o[6] = (short)f2bf(v1 * db[2]); o[7] = (short)f2bf(v1 * db[3]);
      int pos = pairIdx ^ (cc & 7);
      *(short8*)&Hs[((size_t)(b * NKT + kt) * HC + cc) * 64 + pos * 8] = o;
    }
  }
}

// ---------------------------------------------------------------------------
// Kernel 3: out[b,i,c] = silu(Sum_k Ap[i,k]*Hs[k,c] + bias) * mask
// 64(i) x 128(c) tile, BK=64. v2: double-buffered LDS pipeline (2-phase
// template): issue kt+1's global_load_lds BEFORE computing kt, single
// __syncthreads per iter (its vmcnt(0) drain == depth-1 pipeline wait).
// mode 0: store hout, batches reversed (L3: consume most-recently-written
// Ap first).  mode 1: write per-(b,itile) pool partials to gpart.
// ---------------------------------------------------------------------------
__global__ __launch_bounds__(256) void agg_kernel(
    const unsigned short* __restrict__ Ap, const unsigned short* __restrict__ Hs,
    const float* __restrict__ bias, const int* __restrict__ mask,
    float* __restrict__ hout, float* __restrict__ gpart, int mode) {
  __shared__ unsigned short sA[2][64 * 64];   // 2 x 8 KB, swizzled rows
  __shared__ unsigned short sB[2][128 * 64];  // 2 x 16 KB, swizzled rows
  __shared__ float smask[64];
  __shared__ float spool[HC];

  int b = blockIdx.x;
  if (mode == 0) b = BB - 1 - b;  // reverse batch order: L3-resident Ap first
  int i0 = blockIdx.y * 64;
  int t = threadIdx.x;
  int lane = t & 63, w = t >> 6;
  int wm = w >> 1, wn = w & 1;
  int lm = lane & 15, lk = lane >> 4;

  if (t < 64) smask[t] = (float)mask[b * NN + i0 + t];
  if (t < HC) spool[t] = 0.f;

  const char* Apb = (const char*)(Ap + ((size_t)b * NKT * NN + i0) * 64);
  const char* Hsb = (const char*)(Hs + (size_t)b * NKT * HC * 64);

  f32x4 acc[2][4];
#pragma unroll
  for (int mt = 0; mt < 2; ++mt)
#pragma unroll
    for (int nt = 0; nt < 4; ++nt) acc[mt][nt] = (f32x4){0.f, 0.f, 0.f, 0.f};

  // prologue: stage kt=0 into buffer 0
#pragma unroll
  for (int p = 0; p < 2; ++p)
    glds16(Apb + p * 4096 + t * 16, (char*)&sA[0][0] + p * 4096 + w * 1024);
#pragma unroll
  for (int p = 0; p < 4; ++p)
    glds16(Hsb + p * 4096 + t * 16, (char*)&sB[0][0] + p * 4096 + w * 1024);
  __syncthreads();  // drains vmcnt(0): buf0 ready

  for (int kt = 0; kt < NKT; ++kt) {
    int cur = kt & 1;
    // issue next tile's loads first: flight overlaps this tile's compute.
    // WAR-safe: buf[cur^1] reads finished before previous barrier (lgkmcnt
    // drained there), and all waves passed it before any glds here issues.
    if (kt + 1 < NKT) {
      const char* At = Apb + (size_t)(kt + 1) * NN * 128;
      const char* Bt = Hsb + (size_t)(kt + 1) * HC * 128;
#pragma unroll
      for (int p = 0; p < 2; ++p)
        glds16(At + p * 4096 + t * 16,
               (char*)&sA[cur ^ 1][0] + p * 4096 + w * 1024);
#pragma unroll
      for (int p = 0; p < 4; ++p)
        glds16(Bt + p * 4096 + t * 16,
               (char*)&sB[cur ^ 1][0] + p * 4096 + w * 1024);
    }
    const unsigned short* cA = &sA[cur][0];
    const unsigned short* cB = &sB[cur][0];
#pragma unroll
    for (int kk = 0; kk < 2; ++kk) {
      short8 aF[2], bF[4];
#pragma unroll
      for (int mt = 0; mt < 2; ++mt) {
        int r = wm * 32 + mt * 16 + lm;
        int pos = (kk * 4 + lk) ^ (r & 7);
        aF[mt] = *(const short8*)&cA[r * 64 + pos * 8];
      }
#pragma unroll
      for (int nt = 0; nt < 4; ++nt) {
        int r = wn * 64 + nt * 16 + lm;
        int pos = (kk * 4 + lk) ^ (r & 7);
        bF[nt] = *(const short8*)&cB[r * 64 + pos * 8];
      }
#pragma unroll
      for (int mt = 0; mt < 2; ++mt)
#pragma unroll
        for (int nt = 0; nt < 4; ++nt)
          acc[mt][nt] = __builtin_amdgcn_mfma_f32_16x16x32_bf16(
              aF[mt], bF[nt], acc[mt][nt], 0, 0, 0);
    }
    __syncthreads();  // drains vmcnt(0): next buffer ready; protects buf[cur]
  }

  // epilogue: C/D layout row=(lane>>4)*4+r, col=lane&15 (m89/m91)
  if (mode == 0) {
#pragma unroll
    for (int mt = 0; mt < 2; ++mt) {
#pragma unroll
      for (int r = 0; r < 4; ++r) {
        int row = wm * 32 + mt * 16 + lk * 4 + r;
        float mk = smask[row];
        size_t base = (size_t)(b * NN + i0 + row) * HC;
#pragma unroll
        for (int nt = 0; nt < 4; ++nt) {
          int col = wn * 64 + nt * 16 + lm;
          hout[base + col] = silu_f(acc[mt][nt][r] + bias[col]) * mk;
        }
      }
    }
  } else {
    float psum[4] = {0.f, 0.f, 0.f, 0.f};
#pragma unroll
    for (int mt = 0; mt < 2; ++mt)
#pragma unroll
      for (int r = 0; r < 4; ++r) {
        int row = wm * 32 + mt * 16 + lk * 4 + r;
        float mk = smask[row];
#pragma unroll
        for (int nt = 0; nt < 4; ++nt) {
          int col = wn * 64 + nt * 16 + lm;
          psum[nt] += silu_f(acc[mt][nt][r] + bias[col]) * mk;
        }
      }
#pragma unroll
    for (int nt = 0; nt < 4; ++nt)
      atomicAdd(&spool[wn * 64 + nt * 16 + lm], psum[nt]);
    __syncthreads();
    if (t < HC)
      gpart[((size_t)b * 8 + blockIdx.y) * HC + t] =
          spool[t] * (1.0f / (float)NN);
  }
}

// ---------------------------------------------------------------------------
// Kernel 4: sum 8 pool partials -> silu(g@Wl1+bl1) -> @Wl2+bl2.
// One block (128 thr) per batch. No memset / global atomics needed.
// ---------------------------------------------------------------------------
__global__ __launch_bounds__(128) void mlp_kernel(
    const float* __restrict__ gpart, const float* __restrict__ Wl1,
    const float* __restrict__ bl1, const float* __restrict__ Wl2,
    const float* __restrict__ bl2, float* __restrict__ out) {
  __shared__ float sg[HC];
  __shared__ float sh[HC];
  int b = blockIdx.x, t = threadIdx.x;
  float gv = 0.f;
#pragma unroll
  for (int it = 0; it < 8; ++it) gv += gpart[((size_t)b * 8 + it) * HC + t];
  sg[t] = gv;
  __syncthreads();
  float acc = bl1[t];
  for (int k = 0; k < HC; ++k) acc = fmaf(sg[k], Wl1[k * HC + t], acc);
  sh[t] = silu_f(acc);
  __syncthreads();
  if (t < OUTC) {
    float a2 = bl2[t];
    for (int k = 0; k < HC; ++k) a2 = fmaf(sh[k], Wl2[k * OUTC + t], a2);
    out[b * OUTC + t] = a2;
  }
}

extern "C" void kernel_launch(void* const* d_in, const int* in_sizes, int n_in,
                              void* d_out, int out_size, void* d_ws,
                              size_t ws_size, hipStream_t stream) {
  const float* x   = (const float*)d_in[0];
  const float* adj = (const float*)d_in[1];
  const int*   msk = (const int*)d_in[2];
  const float* W0  = (const float*)d_in[3];
  const float* b0  = (const float*)d_in[4];
  const float* W1  = (const float*)d_in[5];
  const float* b1  = (const float*)d_in[6];
  const float* Wl1 = (const float*)d_in[7];
  const float* bl1 = (const float*)d_in[8];
  const float* Wl2 = (const float*)d_in[9];
  const float* bl2 = (const float*)d_in[10];
  float* out = (float*)d_out;

  // workspace layout (~184 MB)
  char* ws = (char*)d_ws;
  float* deg = (float*)ws;                                  // 512 KB
  unsigned short* Hs = (unsigned short*)(ws + (1u << 19));  // 32 MB
  unsigned short* Ap = (unsigned short*)(ws + (1u << 19) + (1u << 25));  // 128 MB
  float* h1 = (float*)(ws + (1u << 19) + (1u << 25) + (1u << 27));       // 16 MB
  float* gp = (float*)(ws + (1u << 19) + (1u << 25) + (1u << 27) + (1u << 24));  // 256 KB

  prep_kernel<<<BB * NN / 4, 256, 0, stream>>>(adj, deg, Ap);
  lin_hs_kernel<<<dim3(NKT, BB), 256, 0, stream>>>(x, W0, deg, Hs, INC);
  agg_kernel<<<dim3(BB, NN / 64), 256, 0, stream>>>(Ap, Hs, b0, msk, h1, gp, 0);
  lin_hs_kernel<<<dim3(NKT, BB), 256, 0, stream>>>(h1, W1, deg, Hs, HC);
  agg_kernel<<<dim3(BB, NN / 64), 256, 0, stream>>>(Ap, Hs, b1, msk, nullptr,
                                                    gp, 1);
  mlp_kernel<<<BB, HC, 0, stream>>>(gp, Wl1, bl1, Wl2, bl2, out);
}

// Round 2
// 548.615 us; speedup vs baseline: 1.0069x; 1.0069x over previous
//
#include <hip/hip_runtime.h>

#define BB 64
#define NN 512
#define FF 4
#define INC 64
#define HC 128
#define OUTC 16
#define KK 2048
#define NKT 32  // K-tiles of 64

// Ap layout: [b][kt][i(512)][64 k-els]  bf16, 16B granules XOR-swizzled by (i&7)
// Hs layout: [b][kt][c(128)][64 k-els]  bf16, granules XOR-swizzled by (c&7)

typedef short short8 __attribute__((ext_vector_type(8)));
typedef float f32x4 __attribute__((ext_vector_type(4)));
typedef float f32x2 __attribute__((ext_vector_type(2)));

__device__ __forceinline__ unsigned short f2bf(float x) {
  union { float f; unsigned u; } v;
  v.f = x;
  unsigned r = v.u + 0x7fffu + ((v.u >> 16) & 1u);  // RNE
  return (unsigned short)(r >> 16);
}

__device__ __forceinline__ float silu_f(float x) {
  return x * (1.0f / (1.0f + __expf(-x)));
}

// async global->LDS, 16B per lane; lptr must be wave-uniform (HW adds lane*16)
__device__ __forceinline__ void glds16(const void* g, void* l) {
  __builtin_amdgcn_global_load_lds(
      (const __attribute__((address_space(1))) void*)g,
      (__attribute__((address_space(3))) void*)l, 16, 0, 0);
}

// ---------------------------------------------------------------------------
// Kernel 1 (prep): one wave per (b,i) row.
//   deg[b,i,f] = rsqrt(max(rowsum(adjhat),1))   (adjhat: diag->1)
//   Ap[b][kt][i][:] = bf16(deg_i[f] * adjhat), swizzled granules
// ---------------------------------------------------------------------------
__global__ __launch_bounds__(256) void prep_kernel(
    const float* __restrict__ adj, float* __restrict__ deg,
    unsigned short* __restrict__ Ap) {
  int wave = blockIdx.x * 4 + (threadIdx.x >> 6);
  int lane = threadIdx.x & 63;
  int b = wave >> 9;
  int i = wave & (NN - 1);
  const float4* row = (const float4*)(adj) + (size_t)(b * NN + i) * NN;
  float4 rv[8];
  float4 s = make_float4(0.f, 0.f, 0.f, 0.f);
#pragma unroll
  for (int jj = 0; jj < 8; ++jj) {
    float4 v = row[jj * 64 + lane];
    if (jj * 64 + lane == i) v = make_float4(1.f, 1.f, 1.f, 1.f);  // diag->1
    rv[jj] = v;
    s.x += v.x; s.y += v.y; s.z += v.z; s.w += v.w;
  }
#pragma unroll
  for (int off = 32; off >= 1; off >>= 1) {
    s.x += __shfl_xor(s.x, off);
    s.y += __shfl_xor(s.y, off);
    s.z += __shfl_xor(s.z, off);
    s.w += __shfl_xor(s.w, off);
  }
  float4 d;
  d.x = rsqrtf(fmaxf(s.x, 1.0f));
  d.y = rsqrtf(fmaxf(s.y, 1.0f));
  d.z = rsqrtf(fmaxf(s.z, 1.0f));
  d.w = rsqrtf(fmaxf(s.w, 1.0f));
  int sw = i & 7;
  int pos = ((lane >> 1) & 7) ^ sw;        // swizzled 16B-granule within row
  int half = lane & 1;                     // 8B half of the granule
#pragma unroll
  for (int jj = 0; jj < 8; ++jj) {
    int kt = jj * 4 + (lane >> 4);
    size_t base = ((size_t)(b * NKT + kt) * NN + i) * 64;
    ushort4 o;
    o.x = f2bf(rv[jj].x * d.x);
    o.y = f2bf(rv[jj].y * d.y);
    o.z = f2bf(rv[jj].z * d.z);
    o.w = f2bf(rv[jj].w * d.w);
    *(ushort4*)&Ap[base + pos * 8 + half * 4] = o;
  }
  if (lane == 0) ((float4*)deg)[b * NN + i] = d;
}

// ---------------------------------------------------------------------------
// Kernel 2: Hs[b][kt][c][k] = deg[b,j,f] * (xin[b,j,:] @ W[:,c])  (bf16)
// One block per kt (16 j-rows). 4 rows x 2 cols per thread:
// halves ds_read_b128 count vs 8x1 and makes x-row addrs wave-uniform
// (gg = t>>6 -> pure LDS broadcast reads, conflict-free).
// ---------------------------------------------------------------------------
__global__ __launch_bounds__(256) void lin_hs_kernel(
    const float* __restrict__ xin, const float* __restrict__ W,
    const float* __restrict__ deg, unsigned short* __restrict__ Hs, int CIN) {
  __shared__ float xt[16 * HC];
  int b = blockIdx.y;
  int kt = blockIdx.x;
  int j0 = kt * 16;
  int t = threadIdx.x;
  {
    const f32x4* src = (const f32x4*)(xin + (size_t)(b * NN + j0) * CIN);
    f32x4* dst = (f32x4*)xt;
    int n4 = 16 * CIN / 4;
    for (int idx = t; idx < n4; idx += 256) dst[idx] = src[idx];
  }
  __syncthreads();

  int c2 = (t & 63) * 2;  // 2 consecutive output cols
  int gg = t >> 6;        // wave-uniform row-group: rows gg*4 .. gg*4+3
  const float* xr = &xt[gg * 4 * CIN];
  float acc[4][2];
#pragma unroll
  for (int r = 0; r < 4; ++r) { acc[r][0] = 0.f; acc[r][1] = 0.f; }

  for (int k = 0; k < CIN; k += 4) {
    f32x2 wv[4];
#pragma unroll
    for (int kk = 0; kk < 4; ++kk)
      wv[kk] = *(const f32x2*)&W[(size_t)(k + kk) * HC + c2];
#pragma unroll
    for (int r = 0; r < 4; ++r) {
      f32x4 xv = *(const f32x4*)&xr[r * CIN + k];
#pragma unroll
      for (int kk = 0; kk < 4; ++kk) {
        acc[r][0] = fmaf(xv[kk], wv[kk][0], acc[r][0]);
        acc[r][1] = fmaf(xv[kk], wv[kk][1], acc[r][1]);
      }
    }
  }

  // fold deg_j, pack bf16 granules (same k-order as before -> bitwise-same Hs)
#pragma unroll
  for (int pr = 0; pr < 2; ++pr) {
    int ja = j0 + gg * 4 + pr * 2;
    f32x4 da = *(const f32x4*)&deg[(size_t)(b * NN + ja) * 4];
    f32x4 db = *(const f32x4*)&deg[(size_t)(b * NN + ja + 1) * 4];
    int pairIdx = gg * 2 + pr;
#pragma unroll
    for (int cq = 0; cq < 2; ++cq) {
      int cc = c2 + cq;
      float v0 = acc[pr * 2][cq];
      float v1 = acc[pr * 2 + 1][cq];
      short8 o;
      o[0] = (short)f2bf(v0 * da[0]); o[1] = (short)f2bf(v0 * da[1]);
      o[2] = (short)f2bf(v0 * da[2]); o[3] = (short)f2bf(v0 * da[3]);
      o[4] = (short)f2bf(v1 * db[0]); o[5] = (short)f2bf(v1 * db[1]);
      o[6] = (short)f2bf(v1 * db[2]); o[7] = (short)f2bf(v1 * db[3]);
      int pos = pairIdx ^ (cc & 7);
      *(short8*)&Hs[((size_t)(b * NKT + kt) * HC + cc) * 64 + pos * 8] = o;
    }
  }
}

// ---------------------------------------------------------------------------
// Kernel 3: out[b,i,c] = silu(Sum_k Ap[i,k]*Hs[k,c] + bias) * mask
// 64(i) x 128(c) tile, BK=64, m97 2-barrier K-loop, global_load_lds staging
// (single buffer — reverted: explicit dbuf regressed, implicit 2-blocks/CU
// overlap already covers the drain; matches learn_hip m99/m100).
// grid (BB, 8): all 8 i-tiles of batch b land on XCD b%8 (Hs L2 reuse).
// mode 0: store hout.  mode 1: write per-(b,itile) pool partials to gpart.
// ---------------------------------------------------------------------------
__global__ __launch_bounds__(256) void agg_kernel(
    const unsigned short* __restrict__ Ap, const unsigned short* __restrict__ Hs,
    const float* __restrict__ bias, const int* __restrict__ mask,
    float* __restrict__ hout, float* __restrict__ gpart, int mode) {
  __shared__ unsigned short sA[64 * 64];   // 8 KB, swizzled rows
  __shared__ unsigned short sB[128 * 64];  // 16 KB, swizzled rows
  __shared__ float smask[64];
  __shared__ float spool[HC];

  int b = blockIdx.x;
  int i0 = blockIdx.y * 64;
  int t = threadIdx.x;
  int lane = t & 63, w = t >> 6;
  int wm = w >> 1, wn = w & 1;
  int lm = lane & 15, lk = lane >> 4;

  if (t < 64) smask[t] = (float)mask[b * NN + i0 + t];
  if (t < HC) spool[t] = 0.f;

  const char* Apb = (const char*)(Ap + ((size_t)b * NKT * NN + i0) * 64);
  const char* Hsb = (const char*)(Hs + (size_t)b * NKT * HC * 64);
  char* sAb = (char*)sA;
  char* sBb = (char*)sB;

  f32x4 acc[2][4];
#pragma unroll
  for (int mt = 0; mt < 2; ++mt)
#pragma unroll
    for (int nt = 0; nt < 4; ++nt) acc[mt][nt] = (f32x4){0.f, 0.f, 0.f, 0.f};

  for (int kt = 0; kt < NKT; ++kt) {
    const char* At = Apb + (size_t)kt * NN * 128;  // this block's 8 KB A tile
    const char* Bt = Hsb + (size_t)kt * HC * 128;  // this batch's 16 KB B tile
#pragma unroll
    for (int p = 0; p < 2; ++p)
      glds16(At + p * 4096 + t * 16, sAb + p * 4096 + w * 1024);
#pragma unroll
    for (int p = 0; p < 4; ++p)
      glds16(Bt + p * 4096 + t * 16, sBb + p * 4096 + w * 1024);
    __syncthreads();  // drains vmcnt (glds counted there)

#pragma unroll
    for (int kk = 0; kk < 2; ++kk) {
      short8 aF[2], bF[4];
#pragma unroll
      for (int mt = 0; mt < 2; ++mt) {
        int r = wm * 32 + mt * 16 + lm;
        int pos = (kk * 4 + lk) ^ (r & 7);
        aF[mt] = *(const short8*)&sA[r * 64 + pos * 8];
      }
#pragma unroll
      for (int nt = 0; nt < 4; ++nt) {
        int r = wn * 64 + nt * 16 + lm;
        int pos = (kk * 4 + lk) ^ (r & 7);
        bF[nt] = *(const short8*)&sB[r * 64 + pos * 8];
      }
#pragma unroll
      for (int mt = 0; mt < 2; ++mt)
#pragma unroll
        for (int nt = 0; nt < 4; ++nt)
          acc[mt][nt] = __builtin_amdgcn_mfma_f32_16x16x32_bf16(
              aF[mt], bF[nt], acc[mt][nt], 0, 0, 0);
    }
    __syncthreads();
  }

  // epilogue: C/D layout row=(lane>>4)*4+r, col=lane&15 (m89/m91)
  if (mode == 0) {
#pragma unroll
    for (int mt = 0; mt < 2; ++mt) {
#pragma unroll
      for (int r = 0; r < 4; ++r) {
        int row = wm * 32 + mt * 16 + lk * 4 + r;
        float mk = smask[row];
        size_t base = (size_t)(b * NN + i0 + row) * HC;
#pragma unroll
        for (int nt = 0; nt < 4; ++nt) {
          int col = wn * 64 + nt * 16 + lm;
          hout[base + col] = silu_f(acc[mt][nt][r] + bias[col]) * mk;
        }
      }
    }
  } else {
    float psum[4] = {0.f, 0.f, 0.f, 0.f};
#pragma unroll
    for (int mt = 0; mt < 2; ++mt)
#pragma unroll
      for (int r = 0; r < 4; ++r) {
        int row = wm * 32 + mt * 16 + lk * 4 + r;
        float mk = smask[row];
#pragma unroll
        for (int nt = 0; nt < 4; ++nt) {
          int col = wn * 64 + nt * 16 + lm;
          psum[nt] += silu_f(acc[mt][nt][r] + bias[col]) * mk;
        }
      }
#pragma unroll
    for (int nt = 0; nt < 4; ++nt)
      atomicAdd(&spool[wn * 64 + nt * 16 + lm], psum[nt]);
    __syncthreads();
    if (t < HC)
      gpart[((size_t)b * 8 + blockIdx.y) * HC + t] =
          spool[t] * (1.0f / (float)NN);
  }
}

// ---------------------------------------------------------------------------
// Kernel 4: sum 8 pool partials -> silu(g@Wl1+bl1) -> @Wl2+bl2.
// One block (128 thr) per batch. No memset / global atomics needed.
// ---------------------------------------------------------------------------
__global__ __launch_bounds__(128) void mlp_kernel(
    const float* __restrict__ gpart, const float* __restrict__ Wl1,
    const float* __restrict__ bl1, const float* __restrict__ Wl2,
    const float* __restrict__ bl2, float* __restrict__ out) {
  __shared__ float sg[HC];
  __shared__ float sh[HC];
  int b = blockIdx.x, t = threadIdx.x;
  float gv = 0.f;
#pragma unroll
  for (int it = 0; it < 8; ++it) gv += gpart[((size_t)b * 8 + it) * HC + t];
  sg[t] = gv;
  __syncthreads();
  float acc = bl1[t];
  for (int k = 0; k < HC; ++k) acc = fmaf(sg[k], Wl1[k * HC + t], acc);
  sh[t] = silu_f(acc);
  __syncthreads();
  if (t < OUTC) {
    float a2 = bl2[t];
    for (int k = 0; k < HC; ++k) a2 = fmaf(sh[k], Wl2[k * OUTC + t], a2);
    out[b * OUTC + t] = a2;
  }
}

extern "C" void kernel_launch(void* const* d_in, const int* in_sizes, int n_in,
                              void* d_out, int out_size, void* d_ws,
                              size_t ws_size, hipStream_t stream) {
  const float* x   = (const float*)d_in[0];
  const float* adj = (const float*)d_in[1];
  const int*   msk = (const int*)d_in[2];
  const float* W0  = (const float*)d_in[3];
  const float* b0  = (const float*)d_in[4];
  const float* W1  = (const float*)d_in[5];
  const float* b1  = (const float*)d_in[6];
  const float* Wl1 = (const float*)d_in[7];
  const float* bl1 = (const float*)d_in[8];
  const float* Wl2 = (const float*)d_in[9];
  const float* bl2 = (const float*)d_in[10];
  float* out = (float*)d_out;

  // workspace layout (~177 MB)
  char* ws = (char*)d_ws;
  float* deg = (float*)ws;                                  // 512 KB
  unsigned short* Hs = (unsigned short*)(ws + (1u << 19));  // 32 MB
  unsigned short* Ap = (unsigned short*)(ws + (1u << 19) + (1u << 25));  // 128 MB
  float* h1 = (float*)(ws + (1u << 19) + (1u << 25) + (1u << 27));       // 16 MB
  float* gp = (float*)(ws + (1u << 19) + (1u << 25) + (1u << 27) + (1u << 24));  // 256 KB

  prep_kernel<<<BB * NN / 4, 256, 0, stream>>>(adj, deg, Ap);
  lin_hs_kernel<<<dim3(NKT, BB), 256, 0, stream>>>(x, W0, deg, Hs, INC);
  agg_kernel<<<dim3(BB, NN / 64), 256, 0, stream>>>(Ap, Hs, b0, msk, h1, gp, 0);
  lin_hs_kernel<<<dim3(NKT, BB), 256, 0, stream>>>(h1, W1, deg, Hs, HC);
  agg_kernel<<<dim3(BB, NN / 64), 256, 0, stream>>>(Ap, Hs, b1, msk, nullptr,
                                                    gp, 1);
  mlp_kernel<<<BB, HC, 0, stream>>>(gp, Wl1, bl1, Wl2, bl2, out);
}